// Round 22
// baseline (4532.486 us; speedup 1.0000x reference)
//
#include <hip/hip_runtime.h>
#include <cstdint>

typedef unsigned short u16;
typedef unsigned int   u32;
typedef __attribute__((ext_vector_type(4))) float f32x4;
typedef __attribute__((ext_vector_type(8))) short s16x8;
typedef __attribute__((ext_vector_type(2))) _Float16 f16x2;

#define NL 3
#define NC 4
#define NB 16
#define NT 4096
#define MR (NB*NT)   // 65536 rows
#define LOG2E  1.44269504f
#define LOG2E2 2.88539008f

__device__ __forceinline__ u16 f2bf(float f){
    u32 u = __float_as_uint(f);
    u32 r = u + 0x7fffu + ((u >> 16) & 1u);
    return (u16)(r >> 16);
}
__device__ __forceinline__ u32 pk2(float x, float y){
    return (u32)f2bf(x) | ((u32)f2bf(y) << 16);
}
__device__ __forceinline__ u16 f2h(float f){
    _Float16 h = (_Float16)f;            // v_cvt_f16_f32, RNE
    return *(u16*)&h;
}
__device__ __forceinline__ u32 pkh(float x, float y){
    return (u32)f2h(x) | ((u32)f2h(y) << 16);
}

// ---------------- weight prep ----------------
__global__ void k_w_to_bf16(const float* __restrict__ src, u16* __restrict__ dst, int n){
    int i = blockIdx.x * 256 + threadIdx.x;
    if (i < n) dst[i] = f2bf(src[i]);
}
// Wih * exp(-ls) * per-gate exp2 prescale (r,z: log2e; n: 2*log2e)
__global__ void k_scale_wih_bf16(const float* __restrict__ wih, const float* __restrict__ ls,
                                 u16* __restrict__ dst, int n){
    int i = blockIdx.x * 256 + threadIdx.x;
    if (i >= n) return;
    int lc  = i / (192 * 256);         // 0..11 -> (layer*4 + channel)
    int row = (i / 256) % 192;         // row within 192-block: gate = row>>6
    float sc = expf(-ls[lc]) * ((row < 128) ? LOG2E : LOG2E2);
    dst[i] = f2bf(wih[i] * sc);
}
// gru_b with matching per-gate prescale -> f32 copy
__global__ void k_scale_gb(const float* __restrict__ gb, float* __restrict__ dst, int n){
    int i = blockIdx.x * 256 + threadIdx.x;
    if (i >= n) return;
    int row = i % 192;                 // within (c,gate*64+j)
    dst[i] = gb[i] * ((row < 128) ? LOG2E : LOG2E2);
}

// ---------------- MFMA GEMM: UNCHANGED from passing round 14 -----------------
template<int AY>
__global__ __launch_bounds__(256) void k_gemm_mfma(
    const float* __restrict__ A, const u16* __restrict__ W,
    const float* __restrict__ bias, float* __restrict__ Cdst,
    int M, int N, int K, int act)
{
    __shared__ u16 lA[128][40];
    __shared__ u16 lB[128][40];

    const int tid  = threadIdx.x;
    const int bm   = blockIdx.x, bn = blockIdx.y;
    const int lane = tid & 63;
    const int wv   = tid >> 6;
    const int wm   = wv >> 1, wn = wv & 1;
    const int r    = tid >> 1;
    const int kh   = (tid & 1) * 16;

    f32x4 acc[4][4];
    #pragma unroll
    for (int i = 0; i < 4; i++)
        #pragma unroll
        for (int j = 0; j < 4; j++)
            acc[i][j] = f32x4{0.f, 0.f, 0.f, 0.f};

    const int fr = lane & 15;
    const int fk = (lane >> 4) * 8;

    for (int kk = 0; kk < K; kk += 32) {
        const float* ap;
        if (AY) {
            int col = kk + kh;
            ap = A + (size_t)(col >> 6) * ((size_t)MR * 64)
                   + (size_t)(bm * 128 + r) * 64 + (col & 63);
        } else {
            ap = A + (size_t)(bm * 128 + r) * K + kk + kh;
        }
        const u16* bp = W + (size_t)(bn * 128 + r) * K + kk + kh;

        float4 a0 = *(const float4*)(ap);
        float4 a1 = *(const float4*)(ap + 4);
        float4 a2 = *(const float4*)(ap + 8);
        float4 a3 = *(const float4*)(ap + 12);
        uint4  b0 = *(const uint4*)(bp);
        uint4  b1 = *(const uint4*)(bp + 8);

        uint4 pa0, pa1;
        pa0.x = pk2(a0.x, a0.y); pa0.y = pk2(a0.z, a0.w);
        pa0.z = pk2(a1.x, a1.y); pa0.w = pk2(a1.z, a1.w);
        pa1.x = pk2(a2.x, a2.y); pa1.y = pk2(a2.z, a2.w);
        pa1.z = pk2(a3.x, a3.y); pa1.w = pk2(a3.z, a3.w);

        __syncthreads();
        *(uint4*)&lA[r][kh]     = pa0;
        *(uint4*)&lA[r][kh + 8] = pa1;
        *(uint4*)&lB[r][kh]     = b0;
        *(uint4*)&lB[r][kh + 8] = b1;
        __syncthreads();

        s16x8 af[4], bf[4];
        #pragma unroll
        for (int f = 0; f < 4; f++) {
            af[f] = *(const s16x8*)&lA[wm * 64 + f * 16 + fr][fk];
            bf[f] = *(const s16x8*)&lB[wn * 64 + f * 16 + fr][fk];
        }
        #pragma unroll
        for (int i = 0; i < 4; i++)
            #pragma unroll
            for (int j = 0; j < 4; j++)
                acc[i][j] = __builtin_amdgcn_mfma_f32_16x16x32_bf16(af[i], bf[j], acc[i][j], 0, 0, 0);
    }

    #pragma unroll
    for (int i = 0; i < 4; i++) {
        int row0 = bm * 128 + wm * 64 + i * 16 + (lane >> 4) * 4;
        #pragma unroll
        for (int j = 0; j < 4; j++) {
            int col = bn * 128 + wn * 64 + j * 16 + (lane & 15);
            float bia = bias[col];
            #pragma unroll
            for (int q = 0; q < 4; q++) {
                float v = acc[i][j][q] + bia;
                if (act) v = tanhf(v);
                Cdst[(size_t)(row0 + q) * N + col] = v;
            }
        }
    }
}

// ---------------- GRU scan: r21 + light fence (DS-only pin) ------------------
// Single wave per (c,b). Weights 96 packed-fp16x2 (pre-scaled log2e/2log2e).
// Fence rationale: the r17/r18 hazard was DS_READ (h uint4 load) hoisting
// above DS_WRITE (h u16 store) via the TBAA hole. Only DS ordering matters ->
// sched_barrier(0x77) lets ALU/VALU/SALU/VMEM cross (tail VALU sinks into the
// next step's LDS-read shadow) while pinning all DS classes. IR-level motion
// still blocked by the asm memory clobber.
__device__ __forceinline__ float vexp2(float x){
    float r; asm("v_exp_f32 %0, %1" : "=v"(r) : "v"(x)); return r;
}
__device__ __forceinline__ float vrcp(float x){
    float r; asm("v_rcp_f32 %0, %1" : "=v"(r) : "v"(x)); return r;
}
__device__ __forceinline__ void mem_fence_light(){
    asm volatile("" ::: "memory");
    // allow ALU|VALU|SALU|VMEM|VMEM_READ|VMEM_WRITE (0x77); block MFMA + DS*
    __builtin_amdgcn_sched_barrier(0x77);
}
__device__ __forceinline__ float d2(float acc, u32 h2, u32 w2){
    union { u32 u; f16x2 v; } a, b;
    a.u = h2; b.u = w2;
    return __builtin_amdgcn_fdot2(a.v, b.v, acc, false);
}

__global__ __launch_bounds__(64, 1) void k_scanb(
    const float* __restrict__ ig,   // (bch*NT,768): prescaled gate inputs (bias added)
    const float* __restrict__ Whh,  // layer base: (C,192,64), raw f32
    const float* __restrict__ bnp,  // (C,64) raw
    const float* __restrict__ lsp,  // (C)
    const float* __restrict__ h0p,  // (C,B,64) layer base
    float* __restrict__ ynew,       // layer base: (C,B,T,64) f32 (d_out)
    int b0)
{
    const int c  = blockIdx.x;
    const int lb = blockIdx.y;
    const int b  = b0 + lb;
    const int j  = threadIdx.x;     // 0..63

    // pack this lane's 3 gate rows as fp16x2, pre-scaled for exp2 forms
    u32 wr[32], wz[32], wn[32];
    {
        const float* pr = Whh + (size_t)(c * 192 +       j) * 64;
        const float* pz = Whh + (size_t)(c * 192 +  64 + j) * 64;
        const float* pn = Whh + (size_t)(c * 192 + 128 + j) * 64;
        #pragma unroll
        for (int i = 0; i < 32; i++) {
            wr[i] = pkh(pr[2*i] * LOG2E,  pr[2*i+1] * LOG2E);
            wz[i] = pkh(pz[2*i] * LOG2E,  pz[2*i+1] * LOG2E);
            wn[i] = pkh(pn[2*i] * LOG2E2, pn[2*i+1] * LOG2E2);
        }
    }

    __shared__ __align__(16) u32 hshb[32];  // 64 fp16 h values
    __shared__ float ring[512];             // 8 steps x 64 units
    float hj = h0p[(c * NB + b) * 64 + j];
    ((u16*)hshb)[j] = f2h(hj);              // single wave: no barrier needed

    const float rs  = expf(-lsp[c]);           // 1/s
    const float bnj = bnp[c * 64 + j] * LOG2E2;

    const float* igp = ig + (size_t)(lb * NT) * 768 + c * 192;
    float* yrow = ynew + (size_t)(c * NB + b) * NT * 64;

    const uint4* hq = (const uint4*)hshb;   // 8 uniform b128 reads = all 64 h

    float A0[8], A1[8], A2[8], B0[8], B1[8], B2[8];
    #pragma unroll
    for (int s = 0; s < 8; s++) {
        const float* p = igp + (size_t)s * 768;
        A0[s] = p[j]; A1[s] = p[64 + j]; A2[s] = p[128 + j];
    }

    auto step = [&](float igr, float igz, float ign, int s){
        // light fence: h reads can't hoist above previous h store (DS pinned)
        mem_fence_light();
        float ar0 = 0.f, ar1 = 0.f, az0 = 0.f, az1 = 0.f, an0 = 0.f, an1 = 0.f;
        #pragma unroll
        for (int i = 0; i < 8; i++) {
            uint4 hv = hq[i];
            ar0 = d2(ar0, hv.x, wr[4*i]);     az0 = d2(az0, hv.x, wz[4*i]);     an0 = d2(an0, hv.x, wn[4*i]);
            ar1 = d2(ar1, hv.y, wr[4*i+1]);   az1 = d2(az1, hv.y, wz[4*i+1]);   an1 = d2(an1, hv.y, wn[4*i+1]);
            ar0 = d2(ar0, hv.z, wr[4*i+2]);   az0 = d2(az0, hv.z, wz[4*i+2]);   an0 = d2(an0, hv.z, wn[4*i+2]);
            ar1 = d2(ar1, hv.w, wr[4*i+3]);   az1 = d2(az1, hv.w, wz[4*i+3]);   an1 = d2(an1, hv.w, wn[4*i+3]);
        }
        // inputs pre-scaled: xr,xz by log2e; n-side by 2*log2e
        float xr = igr + (ar0 + ar1);
        float xz = igz + (az0 + az1);
        float r  = vrcp(1.0f + vexp2(-xr));        // sigmoid
        float zc = vrcp(1.0f + vexp2(xz));         // 1 - z
        float vn = fmaf(r, (an0 + an1) + bnj, ign);
        float e  = vexp2(-fabsf(vn));              // e^{-2|v|} = 2^{-|v2|}
        float n  = copysignf((1.0f - e) * vrcp(1.0f + e), vn);
        float y  = fmaf((n - hj) * zc, rs, hj);    // h + (n-h)(1-z)/s
        ((u16*)hshb)[j] = f2h(y);            // in-order DS pipe orders vs next reads
        ring[s * 64 + j] = y;
        hj = y;
    };
    auto flush = [&](float* dst){
        float4 v0 = *(const float4*)&ring[4 * j];
        float4 v1 = *(const float4*)&ring[256 + 4 * j];
        *(float4*)(dst + 4 * j)       = v0;
        *(float4*)(dst + 256 + 4 * j) = v1;
    };

    for (int t0 = 0; t0 < NT; t0 += 16) {
        #pragma unroll
        for (int s = 0; s < 8; s++) {
            const float* p = igp + (size_t)(t0 + 8 + s) * 768;
            B0[s] = p[j]; B1[s] = p[64 + j]; B2[s] = p[128 + j];
        }
        #pragma unroll
        for (int s = 0; s < 8; s++) step(A0[s], A1[s], A2[s], s);
        flush(yrow + (size_t)t0 * 64);

        if (t0 + 16 < NT) {
            #pragma unroll
            for (int s = 0; s < 8; s++) {
                const float* p = igp + (size_t)(t0 + 16 + s) * 768;
                A0[s] = p[j]; A1[s] = p[64 + j]; A2[s] = p[128 + j];
            }
        }
        #pragma unroll
        for (int s = 0; s < 8; s++) step(B0[s], B1[s], B2[s], s);
        flush(yrow + (size_t)(t0 + 8) * 64);
    }
}

// ---------------- launch ----------------
extern "C" void kernel_launch(void* const* d_in, const int* in_sizes, int n_in,
                              void* d_out, int out_size, void* d_ws, size_t ws_size,
                              hipStream_t stream)
{
    const float* in_inputs = (const float*)d_in[0];
    const float* h0    = (const float*)d_in[1];
    const float* encW1 = (const float*)d_in[3];
    const float* encB1 = (const float*)d_in[4];
    const float* encW2 = (const float*)d_in[5];
    const float* encB2 = (const float*)d_in[6];
    const float* gWih  = (const float*)d_in[7];
    const float* gWhh  = (const float*)d_in[8];
    const float* gB    = (const float*)d_in[9];
    const float* gBn   = (const float*)d_in[10];
    const float* logS  = (const float*)d_in[11];
    const float* mW1   = (const float*)d_in[12];
    const float* mB1   = (const float*)d_in[13];
    const float* mW2   = (const float*)d_in[14];
    const float* mB2   = (const float*)d_in[15];

    float* out_f  = (float*)d_out;                    // (B,T,256) f32
    float* ynew_f = out_f + (size_t)MR * 256;         // (L,C,B,T,64) f32

    // ---- adaptive chunking ----
    const size_t xa_b  = (size_t)MR * 256 * 4;                 // 67.11 MB
    const size_t wb_b  = ((size_t)256*128 + 256*256 + (size_t)NL*NC*192*256
                          + 2*(size_t)NL*256*256) * 2 + (size_t)NL*768*4 + 8192;
    int bch = 16;
    for (;;) {
        size_t igb = (size_t)bch * NT * 768 * 4;
        size_t r0  = igb > xa_b ? igb : xa_b;   // XB aliases region 0
        if (r0 + xa_b + wb_b + 4096 <= ws_size || bch == 1) break;
        bch >>= 1;
    }
    const int nch = NB / bch;
    const int mch = bch * NT;

    char* ws = (char*)d_ws;
    size_t off = 0;
    auto alloc = [&](size_t bytes) -> void* {
        void* p = ws + off;
        off = (off + bytes + 255) & ~(size_t)255;
        return p;
    };
    size_t igb = (size_t)bch * NT * 768 * 4;
    float* IG  = (float*)alloc(igb > xa_b ? igb : xa_b);  // region 0
    float* XB  = IG;                                       // alias: lifetimes disjoint
    float* XA  = (float*)alloc(xa_b);
    u16* WE1b  = (u16*)alloc((size_t)256 * 128 * 2);
    u16* WE2b  = (u16*)alloc((size_t)256 * 256 * 2);
    u16* WIHb  = (u16*)alloc((size_t)NL * NC * 192 * 256 * 2);
    u16* WM1b  = (u16*)alloc((size_t)NL * 256 * 256 * 2);
    u16* WM2b  = (u16*)alloc((size_t)NL * 256 * 256 * 2);
    float* gBs = (float*)alloc((size_t)NL * 768 * 4);

    // weight conversions (once per launch)
    k_w_to_bf16<<<(256*128 + 255) / 256, 256, 0, stream>>>(encW1, WE1b, 256*128);
    k_w_to_bf16<<<(256*256 + 255) / 256, 256, 0, stream>>>(encW2, WE2b, 256*256);
    k_w_to_bf16<<<(NL*256*256 + 255) / 256, 256, 0, stream>>>(mW1, WM1b, NL*256*256);
    k_w_to_bf16<<<(NL*256*256 + 255) / 256, 256, 0, stream>>>(mW2, WM2b, NL*256*256);
    int nWih = NL * NC * 192 * 256;
    k_scale_wih_bf16<<<(nWih + 255) / 256, 256, 0, stream>>>(gWih, logS, WIHb, nWih);
    k_scale_gb<<<(NL*768 + 255) / 256, 256, 0, stream>>>(gB, gBs, NL*768);

    dim3 blk(256);
    // encoder: XB = tanh(inputs @ W1^T + b1); XA = XB @ W2^T + b2
    k_gemm_mfma<0><<<dim3(MR / 128, 2), blk, 0, stream>>>(in_inputs, WE1b, encB1, XB, MR, 256, 128, 1);
    k_gemm_mfma<0><<<dim3(MR / 128, 2), blk, 0, stream>>>(XB, WE2b, encB2, XA, MR, 256, 256, 0);

    for (int l = 0; l < NL; l++) {
        float* ylayer = ynew_f + (size_t)l * NC * NB * NT * 64;
        for (int ch = 0; ch < nch; ch++) {
            k_gemm_mfma<0><<<dim3(mch / 128, 6), blk, 0, stream>>>(
                XA + (size_t)ch * mch * 256, WIHb + (size_t)l * NC * 192 * 256,
                gBs + l * 768, IG, mch, 768, 256, 0);
            k_scanb<<<dim3(NC, bch), dim3(64), 0, stream>>>(
                IG, gWhh + (size_t)l * NC * 192 * 64, gBn + l * NC * 64, logS + l * NC,
                h0 + (size_t)l * NC * NB * 64, ylayer, ch * bch);
        }
        // inter-layer MLP reads A straight from ynew layout
        k_gemm_mfma<1><<<dim3(MR / 128, 2), blk, 0, stream>>>(
            ylayer, WM1b + (size_t)l * 256 * 256, mB1 + l * 256, XB, MR, 256, 256, 1);
        k_gemm_mfma<0><<<dim3(MR / 128, 2), blk, 0, stream>>>(
            XB, WM2b + (size_t)l * 256 * 256, mB2 + l * 256, XA, MR, 256, 256, 0);
    }
    // faithful to source: mlps[-1] applied a second time -> out (f32)
    k_gemm_mfma<0><<<dim3(MR / 128, 2), blk, 0, stream>>>(
        XA, WM1b + (size_t)2 * 256 * 256, mB1 + 2 * 256, XB, MR, 256, 256, 1);
    k_gemm_mfma<0><<<dim3(MR / 128, 2), blk, 0, stream>>>(
        XB, WM2b + (size_t)2 * 256 * 256, mB2 + 2 * 256, out_f, MR, 256, 256, 0);
}

// Round 23
// 4457.754 us; speedup vs baseline: 1.0168x; 1.0168x over previous
//
#include <hip/hip_runtime.h>
#include <cstdint>

typedef unsigned short u16;
typedef unsigned int   u32;
typedef __attribute__((ext_vector_type(4))) float f32x4;
typedef __attribute__((ext_vector_type(8))) short s16x8;
typedef __attribute__((ext_vector_type(2))) _Float16 f16x2;

#define NL 3
#define NC 4
#define NB 16
#define NT 4096
#define MR (NB*NT)   // 65536 rows
#define LOG2E  1.44269504f
#define LOG2E2 2.88539008f

__device__ __forceinline__ u16 f2bf(float f){
    u32 u = __float_as_uint(f);
    u32 r = u + 0x7fffu + ((u >> 16) & 1u);
    return (u16)(r >> 16);
}
__device__ __forceinline__ u32 pk2(float x, float y){
    return (u32)f2bf(x) | ((u32)f2bf(y) << 16);
}
__device__ __forceinline__ u16 f2h(float f){
    _Float16 h = (_Float16)f;            // v_cvt_f16_f32, RNE
    return *(u16*)&h;
}
__device__ __forceinline__ u32 pkh(float x, float y){
    return (u32)f2h(x) | ((u32)f2h(y) << 16);
}

// ---------------- weight prep ----------------
__global__ void k_w_to_bf16(const float* __restrict__ src, u16* __restrict__ dst, int n){
    int i = blockIdx.x * 256 + threadIdx.x;
    if (i < n) dst[i] = f2bf(src[i]);
}
// Wih * exp(-ls) * per-gate exp2 prescale (r,z: log2e; n: 2*log2e)
__global__ void k_scale_wih_bf16(const float* __restrict__ wih, const float* __restrict__ ls,
                                 u16* __restrict__ dst, int n){
    int i = blockIdx.x * 256 + threadIdx.x;
    if (i >= n) return;
    int lc  = i / (192 * 256);         // 0..11 -> (layer*4 + channel)
    int row = (i / 256) % 192;         // row within 192-block: gate = row>>6
    float sc = expf(-ls[lc]) * ((row < 128) ? LOG2E : LOG2E2);
    dst[i] = f2bf(wih[i] * sc);
}
// gru_b with matching per-gate prescale -> f32 copy
__global__ void k_scale_gb(const float* __restrict__ gb, float* __restrict__ dst, int n){
    int i = blockIdx.x * 256 + threadIdx.x;
    if (i >= n) return;
    int row = i % 192;                 // within (c,gate*64+j)
    dst[i] = gb[i] * ((row < 128) ? LOG2E : LOG2E2);
}

// ---------------- MFMA GEMM: UNCHANGED from passing round 14 -----------------
template<int AY>
__global__ __launch_bounds__(256) void k_gemm_mfma(
    const float* __restrict__ A, const u16* __restrict__ W,
    const float* __restrict__ bias, float* __restrict__ Cdst,
    int M, int N, int K, int act)
{
    __shared__ u16 lA[128][40];
    __shared__ u16 lB[128][40];

    const int tid  = threadIdx.x;
    const int bm   = blockIdx.x, bn = blockIdx.y;
    const int lane = tid & 63;
    const int wv   = tid >> 6;
    const int wm   = wv >> 1, wn = wv & 1;
    const int r    = tid >> 1;
    const int kh   = (tid & 1) * 16;

    f32x4 acc[4][4];
    #pragma unroll
    for (int i = 0; i < 4; i++)
        #pragma unroll
        for (int j = 0; j < 4; j++)
            acc[i][j] = f32x4{0.f, 0.f, 0.f, 0.f};

    const int fr = lane & 15;
    const int fk = (lane >> 4) * 8;

    for (int kk = 0; kk < K; kk += 32) {
        const float* ap;
        if (AY) {
            int col = kk + kh;
            ap = A + (size_t)(col >> 6) * ((size_t)MR * 64)
                   + (size_t)(bm * 128 + r) * 64 + (col & 63);
        } else {
            ap = A + (size_t)(bm * 128 + r) * K + kk + kh;
        }
        const u16* bp = W + (size_t)(bn * 128 + r) * K + kk + kh;

        float4 a0 = *(const float4*)(ap);
        float4 a1 = *(const float4*)(ap + 4);
        float4 a2 = *(const float4*)(ap + 8);
        float4 a3 = *(const float4*)(ap + 12);
        uint4  b0 = *(const uint4*)(bp);
        uint4  b1 = *(const uint4*)(bp + 8);

        uint4 pa0, pa1;
        pa0.x = pk2(a0.x, a0.y); pa0.y = pk2(a0.z, a0.w);
        pa0.z = pk2(a1.x, a1.y); pa0.w = pk2(a1.z, a1.w);
        pa1.x = pk2(a2.x, a2.y); pa1.y = pk2(a2.z, a2.w);
        pa1.z = pk2(a3.x, a3.y); pa1.w = pk2(a3.z, a3.w);

        __syncthreads();
        *(uint4*)&lA[r][kh]     = pa0;
        *(uint4*)&lA[r][kh + 8] = pa1;
        *(uint4*)&lB[r][kh]     = b0;
        *(uint4*)&lB[r][kh + 8] = b1;
        __syncthreads();

        s16x8 af[4], bf[4];
        #pragma unroll
        for (int f = 0; f < 4; f++) {
            af[f] = *(const s16x8*)&lA[wm * 64 + f * 16 + fr][fk];
            bf[f] = *(const s16x8*)&lB[wn * 64 + f * 16 + fr][fk];
        }
        #pragma unroll
        for (int i = 0; i < 4; i++)
            #pragma unroll
            for (int j = 0; j < 4; j++)
                acc[i][j] = __builtin_amdgcn_mfma_f32_16x16x32_bf16(af[i], bf[j], acc[i][j], 0, 0, 0);
    }

    #pragma unroll
    for (int i = 0; i < 4; i++) {
        int row0 = bm * 128 + wm * 64 + i * 16 + (lane >> 4) * 4;
        #pragma unroll
        for (int j = 0; j < 4; j++) {
            int col = bn * 128 + wn * 64 + j * 16 + (lane & 15);
            float bia = bias[col];
            #pragma unroll
            for (int q = 0; q < 4; q++) {
                float v = acc[i][j][q] + bia;
                if (act) v = tanhf(v);
                Cdst[(size_t)(row0 + q) * N + col] = v;
            }
        }
    }
}

// ---------------- GRU scan: r21 + per-iteration VGPR pin of weights ----------
// Single wave per (c,b). Weights 96 packed-fp16x2, pre-scaled log2e/2log2e.
// VGPR_Count=92 proved the allocator parks the invariant weights in AGPRs ->
// v_accvgpr_read per dot2 operand (~192 cy/step). The "+v" pin at each outer
// iteration forces them into arch VGPRs (copies amortize over 16 steps).
// Fences identical to proven r21 (full sched_barrier(0) + memory clobber).
__device__ __forceinline__ float vexp2(float x){
    float r; asm("v_exp_f32 %0, %1" : "=v"(r) : "v"(x)); return r;
}
__device__ __forceinline__ float vrcp(float x){
    float r; asm("v_rcp_f32 %0, %1" : "=v"(r) : "v"(x)); return r;
}
__device__ __forceinline__ void mem_fence_compiler(){
    asm volatile("" ::: "memory");
    __builtin_amdgcn_sched_barrier(0);
}
__device__ __forceinline__ float d2(float acc, u32 h2, u32 w2){
    union { u32 u; f16x2 v; } a, b;
    a.u = h2; b.u = w2;
    return __builtin_amdgcn_fdot2(a.v, b.v, acc, false);
}

__global__ __launch_bounds__(64, 1) void k_scanb(
    const float* __restrict__ ig,   // (bch*NT,768): prescaled gate inputs (bias added)
    const float* __restrict__ Whh,  // layer base: (C,192,64), raw f32
    const float* __restrict__ bnp,  // (C,64) raw
    const float* __restrict__ lsp,  // (C)
    const float* __restrict__ h0p,  // (C,B,64) layer base
    float* __restrict__ ynew,       // layer base: (C,B,T,64) f32 (d_out)
    int b0)
{
    const int c  = blockIdx.x;
    const int lb = blockIdx.y;
    const int b  = b0 + lb;
    const int j  = threadIdx.x;     // 0..63

    // pack this lane's 3 gate rows as fp16x2, pre-scaled for exp2 forms
    u32 wr[32], wz[32], wn[32];
    {
        const float* pr = Whh + (size_t)(c * 192 +       j) * 64;
        const float* pz = Whh + (size_t)(c * 192 +  64 + j) * 64;
        const float* pn = Whh + (size_t)(c * 192 + 128 + j) * 64;
        #pragma unroll
        for (int i = 0; i < 32; i++) {
            wr[i] = pkh(pr[2*i] * LOG2E,  pr[2*i+1] * LOG2E);
            wz[i] = pkh(pz[2*i] * LOG2E,  pz[2*i+1] * LOG2E);
            wn[i] = pkh(pn[2*i] * LOG2E2, pn[2*i+1] * LOG2E2);
        }
    }

    __shared__ __align__(16) u32 hshb[32];  // 64 fp16 h values
    __shared__ float ring[512];             // 8 steps x 64 units
    float hj = h0p[(c * NB + b) * 64 + j];
    ((u16*)hshb)[j] = f2h(hj);              // single wave: no barrier needed

    const float rs  = expf(-lsp[c]);           // 1/s
    const float bnj = bnp[c * 64 + j] * LOG2E2;

    const float* igp = ig + (size_t)(lb * NT) * 768 + c * 192;
    float* yrow = ynew + (size_t)(c * NB + b) * NT * 64;

    const uint4* hq = (const uint4*)hshb;   // 8 uniform b128 reads = all 64 h

    float A0[8], A1[8], A2[8], B0[8], B1[8], B2[8];
    #pragma unroll
    for (int s = 0; s < 8; s++) {
        const float* p = igp + (size_t)s * 768;
        A0[s] = p[j]; A1[s] = p[64 + j]; A2[s] = p[128 + j];
    }

    auto step = [&](float igr, float igz, float ign, int s){
        // fence: h reads must not hoist above previous step's h store (TBAA)
        mem_fence_compiler();
        float ar0 = 0.f, ar1 = 0.f, az0 = 0.f, az1 = 0.f, an0 = 0.f, an1 = 0.f;
        #pragma unroll
        for (int i = 0; i < 8; i++) {
            uint4 hv = hq[i];
            ar0 = d2(ar0, hv.x, wr[4*i]);     az0 = d2(az0, hv.x, wz[4*i]);     an0 = d2(an0, hv.x, wn[4*i]);
            ar1 = d2(ar1, hv.y, wr[4*i+1]);   az1 = d2(az1, hv.y, wz[4*i+1]);   an1 = d2(an1, hv.y, wn[4*i+1]);
            ar0 = d2(ar0, hv.z, wr[4*i+2]);   az0 = d2(az0, hv.z, wz[4*i+2]);   an0 = d2(an0, hv.z, wn[4*i+2]);
            ar1 = d2(ar1, hv.w, wr[4*i+3]);   az1 = d2(az1, hv.w, wz[4*i+3]);   an1 = d2(an1, hv.w, wn[4*i+3]);
        }
        // inputs pre-scaled: xr,xz by log2e; n-side by 2*log2e
        float xr = igr + (ar0 + ar1);
        float xz = igz + (az0 + az1);
        float r  = vrcp(1.0f + vexp2(-xr));        // sigmoid
        float zc = vrcp(1.0f + vexp2(xz));         // 1 - z
        float vn = fmaf(r, (an0 + an1) + bnj, ign);
        float e  = vexp2(-fabsf(vn));              // e^{-2|v|} = 2^{-|v2|}
        float n  = copysignf((1.0f - e) * vrcp(1.0f + e), vn);
        float y  = fmaf((n - hj) * zc, rs, hj);    // h + (n-h)(1-z)/s
        ((u16*)hshb)[j] = f2h(y);            // in-order DS pipe orders vs next reads
        ring[s * 64 + j] = y;
        hj = y;
    };
    auto flush = [&](float* dst){
        float4 v0 = *(const float4*)&ring[4 * j];
        float4 v1 = *(const float4*)&ring[256 + 4 * j];
        *(float4*)(dst + 4 * j)       = v0;
        *(float4*)(dst + 256 + 4 * j) = v1;
    };

    for (int t0 = 0; t0 < NT; t0 += 16) {
        // pin weights into arch VGPRs once per 16 steps (defeat AGPR parking)
        #pragma unroll
        for (int i = 0; i < 32; i++)
            asm volatile("" : "+v"(wr[i]), "+v"(wz[i]), "+v"(wn[i]));

        #pragma unroll
        for (int s = 0; s < 8; s++) {
            const float* p = igp + (size_t)(t0 + 8 + s) * 768;
            B0[s] = p[j]; B1[s] = p[64 + j]; B2[s] = p[128 + j];
        }
        #pragma unroll
        for (int s = 0; s < 8; s++) step(A0[s], A1[s], A2[s], s);
        flush(yrow + (size_t)t0 * 64);

        if (t0 + 16 < NT) {
            #pragma unroll
            for (int s = 0; s < 8; s++) {
                const float* p = igp + (size_t)(t0 + 16 + s) * 768;
                A0[s] = p[j]; A1[s] = p[64 + j]; A2[s] = p[128 + j];
            }
        }
        #pragma unroll
        for (int s = 0; s < 8; s++) step(B0[s], B1[s], B2[s], s);
        flush(yrow + (size_t)(t0 + 8) * 64);
    }
}

// ---------------- launch ----------------
extern "C" void kernel_launch(void* const* d_in, const int* in_sizes, int n_in,
                              void* d_out, int out_size, void* d_ws, size_t ws_size,
                              hipStream_t stream)
{
    const float* in_inputs = (const float*)d_in[0];
    const float* h0    = (const float*)d_in[1];
    const float* encW1 = (const float*)d_in[3];
    const float* encB1 = (const float*)d_in[4];
    const float* encW2 = (const float*)d_in[5];
    const float* encB2 = (const float*)d_in[6];
    const float* gWih  = (const float*)d_in[7];
    const float* gWhh  = (const float*)d_in[8];
    const float* gB    = (const float*)d_in[9];
    const float* gBn   = (const float*)d_in[10];
    const float* logS  = (const float*)d_in[11];
    const float* mW1   = (const float*)d_in[12];
    const float* mB1   = (const float*)d_in[13];
    const float* mW2   = (const float*)d_in[14];
    const float* mB2   = (const float*)d_in[15];

    float* out_f  = (float*)d_out;                    // (B,T,256) f32
    float* ynew_f = out_f + (size_t)MR * 256;         // (L,C,B,T,64) f32

    // ---- adaptive chunking ----
    const size_t xa_b  = (size_t)MR * 256 * 4;                 // 67.11 MB
    const size_t wb_b  = ((size_t)256*128 + 256*256 + (size_t)NL*NC*192*256
                          + 2*(size_t)NL*256*256) * 2 + (size_t)NL*768*4 + 8192;
    int bch = 16;
    for (;;) {
        size_t igb = (size_t)bch * NT * 768 * 4;
        size_t r0  = igb > xa_b ? igb : xa_b;   // XB aliases region 0
        if (r0 + xa_b + wb_b + 4096 <= ws_size || bch == 1) break;
        bch >>= 1;
    }
    const int nch = NB / bch;
    const int mch = bch * NT;

    char* ws = (char*)d_ws;
    size_t off = 0;
    auto alloc = [&](size_t bytes) -> void* {
        void* p = ws + off;
        off = (off + bytes + 255) & ~(size_t)255;
        return p;
    };
    size_t igb = (size_t)bch * NT * 768 * 4;
    float* IG  = (float*)alloc(igb > xa_b ? igb : xa_b);  // region 0
    float* XB  = IG;                                       // alias: lifetimes disjoint
    float* XA  = (float*)alloc(xa_b);
    u16* WE1b  = (u16*)alloc((size_t)256 * 128 * 2);
    u16* WE2b  = (u16*)alloc((size_t)256 * 256 * 2);
    u16* WIHb  = (u16*)alloc((size_t)NL * NC * 192 * 256 * 2);
    u16* WM1b  = (u16*)alloc((size_t)NL * 256 * 256 * 2);
    u16* WM2b  = (u16*)alloc((size_t)NL * 256 * 256 * 2);
    float* gBs = (float*)alloc((size_t)NL * 768 * 4);

    // weight conversions (once per launch)
    k_w_to_bf16<<<(256*128 + 255) / 256, 256, 0, stream>>>(encW1, WE1b, 256*128);
    k_w_to_bf16<<<(256*256 + 255) / 256, 256, 0, stream>>>(encW2, WE2b, 256*256);
    k_w_to_bf16<<<(NL*256*256 + 255) / 256, 256, 0, stream>>>(mW1, WM1b, NL*256*256);
    k_w_to_bf16<<<(NL*256*256 + 255) / 256, 256, 0, stream>>>(mW2, WM2b, NL*256*256);
    int nWih = NL * NC * 192 * 256;
    k_scale_wih_bf16<<<(nWih + 255) / 256, 256, 0, stream>>>(gWih, logS, WIHb, nWih);
    k_scale_gb<<<(NL*768 + 255) / 256, 256, 0, stream>>>(gB, gBs, NL*768);

    dim3 blk(256);
    // encoder: XB = tanh(inputs @ W1^T + b1); XA = XB @ W2^T + b2
    k_gemm_mfma<0><<<dim3(MR / 128, 2), blk, 0, stream>>>(in_inputs, WE1b, encB1, XB, MR, 256, 128, 1);
    k_gemm_mfma<0><<<dim3(MR / 128, 2), blk, 0, stream>>>(XB, WE2b, encB2, XA, MR, 256, 256, 0);

    for (int l = 0; l < NL; l++) {
        float* ylayer = ynew_f + (size_t)l * NC * NB * NT * 64;
        for (int ch = 0; ch < nch; ch++) {
            k_gemm_mfma<0><<<dim3(mch / 128, 6), blk, 0, stream>>>(
                XA + (size_t)ch * mch * 256, WIHb + (size_t)l * NC * 192 * 256,
                gBs + l * 768, IG, mch, 768, 256, 0);
            k_scanb<<<dim3(NC, bch), dim3(64), 0, stream>>>(
                IG, gWhh + (size_t)l * NC * 192 * 64, gBn + l * NC * 64, logS + l * NC,
                h0 + (size_t)l * NC * NB * 64, ylayer, ch * bch);
        }
        // inter-layer MLP reads A straight from ynew layout
        k_gemm_mfma<1><<<dim3(MR / 128, 2), blk, 0, stream>>>(
            ylayer, WM1b + (size_t)l * 256 * 256, mB1 + l * 256, XB, MR, 256, 256, 1);
        k_gemm_mfma<0><<<dim3(MR / 128, 2), blk, 0, stream>>>(
            XB, WM2b + (size_t)l * 256 * 256, mB2 + l * 256, XA, MR, 256, 256, 0);
    }
    // faithful to source: mlps[-1] applied a second time -> out (f32)
    k_gemm_mfma<0><<<dim3(MR / 128, 2), blk, 0, stream>>>(
        XA, WM1b + (size_t)2 * 256 * 256, mB1 + 2 * 256, XB, MR, 256, 256, 1);
    k_gemm_mfma<0><<<dim3(MR / 128, 2), blk, 0, stream>>>(
        XB, WM2b + (size_t)2 * 256 * 256, mB2 + 2 * 256, out_f, MR, 256, 256, 0);
}